// Round 14
// baseline (89.542 us; speedup 1.0000x reference)
//
#include <hip/hip_runtime.h>
#include <hip/hip_fp16.h>

#define N_NODES 100000
#define N_EDGES 1600000
#define IN_CH 8
#define N_CLASSES 16
// MAX_ORDER+1 = 2, N_RINGS = 2

// bucket = src >> 6  (64 nodes per bucket)
#define NPB 64
#define NPB_SHIFT 6
#define NB ((N_NODES + NPB - 1) / NPB)                // 1563
#define NB_PAD 1568                                   // multiple of 16
#define BIN_T 4096
#define NBLK ((N_EDGES + BIN_T - 1) / BIN_T)          // 391 (one resident round)
#define MAX_BE 1536   // bucket mean 1024, sigma ~32 -> +16 sigma

union H2I { __half2 h; int i; };

// ---------------- binned-path ws layout (bytes) ----------------
// recbuf: int4[N_EDGES] (16B: 3x half2 payload + packed key)
// bcnt: int[NBLK][NB_PAD]; colsum: int[NB_PAD]; gbase: int[NB+1]
#define RECBUF_OFF  0
#define BCNT_OFF    ((size_t)N_EDGES * 16)
#define COLSUM_OFF  (BCNT_OFF + (size_t)NBLK * NB_PAD * 4)
#define GBASE_OFF   (COLSUM_OFF + (size_t)NB_PAD * 4)
#define BIN_WS_BYTES (GBASE_OFF + ((size_t)NB + 4) * 4)

// ---------------- fallback (atomic) ws layout ----------------
#define AGGR_RE_FLOATS (N_NODES * 32)
#define AGGR_IM_FLOATS (N_NODES * 16)
#define WS_FLOATS (AGGR_RE_FLOATS + AGGR_IM_FLOATS)
#define WS_F4 (WS_FLOATS / 4)

// ======================= binned path =======================

// per-block LDS histogram -> coalesced row write (NO global atomics)
__global__ __launch_bounds__(1024) void hist_kernel(const int* __restrict__ ei,
                                                    int* __restrict__ bcnt) {
    __shared__ int h[NB_PAD];
    int t = threadIdx.x;
    for (int i = t; i < NB_PAD; i += 1024) h[i] = 0;
    __syncthreads();
    int base = blockIdx.x * BIN_T;
    int end = base + BIN_T; if (end > N_EDGES) end = N_EDGES;
    for (int e = base + t; e < end; e += 1024)
        atomicAdd(&h[ei[e] >> NPB_SHIFT], 1);
    __syncthreads();
    for (int i = t; i < NB_PAD; i += 1024)
        bcnt[(size_t)blockIdx.x * NB_PAD + i] = h[i];
}

// 98 blocks x 16 buckets: exclusive scan over NBLK rows per bucket, in-place.
__global__ __launch_bounds__(1024) void colscan_kernel(int* __restrict__ bcnt,
                                                       int* __restrict__ colsum) {
    __shared__ int sbuf[16][65];
    int t = threadIdx.x;
    int r64 = t >> 4, c = t & 15;
    int c0 = blockIdx.x * 16;
    int vals[7];
    int partial = 0;
#pragma unroll
    for (int k = 0; k < 7; ++k) {
        int row = r64 * 7 + k;
        int v = (row < NBLK) ? bcnt[(size_t)row * NB_PAD + c0 + c] : 0;
        vals[k] = v;
        partial += v;
    }
    sbuf[c][r64] = partial;
    __syncthreads();
#pragma unroll
    for (int d = 1; d < 64; d <<= 1) {
        int u = (r64 >= d) ? sbuf[c][r64 - d] : 0;
        __syncthreads();
        sbuf[c][r64] += u;
        __syncthreads();
    }
    int running = sbuf[c][r64] - partial;
#pragma unroll
    for (int k = 0; k < 7; ++k) {
        int row = r64 * 7 + k;
        if (row < NBLK) bcnt[(size_t)row * NB_PAD + c0 + c] = running;
        running += vals[k];
    }
    if (r64 == 63) colsum[c0 + c] = sbuf[c][63];
}

// single block: exclusive scan of colsum (NB entries, 2/thread) -> gbase
__global__ __launch_bounds__(1024) void base_kernel(const int* __restrict__ colsum,
                                                    int* __restrict__ gbase) {
    __shared__ int buf[1024];
    int t = threadIdx.x;
    int i0 = 2 * t, i1 = 2 * t + 1;
    int v0 = (i0 < NB) ? colsum[i0] : 0;
    int v1 = (i1 < NB) ? colsum[i1] : 0;
    buf[t] = v0 + v1;
    __syncthreads();
#pragma unroll
    for (int d = 1; d < 1024; d <<= 1) {
        int u = (t >= d) ? buf[t - d] : 0;
        __syncthreads();
        buf[t] += u;
        __syncthreads();
    }
    int excl = buf[t] - (v0 + v1);
    if (i0 < NB) gbase[i0] = excl;
    if (i1 < NB) gbase[i1] = excl + v0;
    if (t == 1023) gbase[NB] = buf[1023];
}

// bin with in-LDS tile sort: writes to recbuf are sorted by bucket ->
// consecutive threads write consecutive positions (coalesced runs).
// record: (h2(o0r0.re,o0r1.re), h2(o1r0.re,o1r0.im), h2(o1r1.re,o1r1.im), tgt|nl<<17)
__global__ __launch_bounds__(1024) void bin_kernel(
    const int* __restrict__ ei, const float* __restrict__ precomp,
    const int* __restrict__ bcnt, const int* __restrict__ gbase,
    int4* __restrict__ recbuf) {
    __shared__ int lbase[NB];              // 6.2 KB global run base for this tile
    __shared__ int cnt[NB];                // 6.2 KB counts -> cursor
    __shared__ int tstart[NB];             // 6.2 KB tile-local sorted starts
    __shared__ unsigned short sei[BIN_T];  // 8 KB edge offsets in sorted order
    __shared__ int sscan[1024];            // 4 KB scan buffer

    int t = threadIdx.x;
    int base = blockIdx.x * BIN_T;
    int tn = N_EDGES - base; if (tn > BIN_T) tn = BIN_T;

    for (int i = t; i < NB; i += 1024) {
        lbase[i] = gbase[i] + bcnt[(size_t)blockIdx.x * NB_PAD + i];
        cnt[i] = 0;
    }
    __syncthreads();

    // pass A: count buckets in this tile
    for (int k = t; k < tn; k += 1024)
        atomicAdd(&cnt[ei[base + k] >> NPB_SHIFT], 1);
    __syncthreads();

    // exclusive scan of cnt -> tstart (2 entries/thread)
    {
        int i0 = 2 * t, i1 = 2 * t + 1;
        int v0 = (i0 < NB) ? cnt[i0] : 0;
        int v1 = (i1 < NB) ? cnt[i1] : 0;
        sscan[t] = v0 + v1;
        __syncthreads();
#pragma unroll
        for (int d = 1; d < 1024; d <<= 1) {
            int u = (t >= d) ? sscan[t - d] : 0;
            __syncthreads();
            sscan[t] += u;
            __syncthreads();
        }
        int excl = sscan[t] - (v0 + v1);
        if (i0 < NB) tstart[i0] = excl;
        if (i1 < NB) tstart[i1] = excl + v0;
    }
    __syncthreads();
    // cursor = copy of tstart (reuse cnt)
    for (int i = t; i < NB; i += 1024) cnt[i] = tstart[i];
    __syncthreads();

    // pass B: scatter edge offsets into sorted slots (ei tile is L1/L2 hot)
    for (int k = t; k < tn; k += 1024) {
        int b = ei[base + k] >> NPB_SHIFT;
        int s = atomicAdd(&cnt[b], 1);
        sei[s] = (unsigned short)k;
    }
    __syncthreads();

    // pass C: walk sorted slots; position arithmetic (no atomics); coalesced runs
    for (int s = t; s < tn; s += 1024) {
        int k = (int)sei[s];
        int e = base + k;
        int src = ei[e];
        int tgt = ei[N_EDGES + e];
        int b = src >> NPB_SHIFT;
        int pos = lbase[b] + (s - tstart[b]);
        const float4* pc = (const float4*)(precomp + (size_t)e * 8);
        float4 q0 = pc[0], q1 = pc[1];
        H2I u0, u1, u2;
        u0.h = __floats2half2_rn(q0.x, q0.z);
        u1.h = __floats2half2_rn(q1.x, q1.y);
        u2.h = __floats2half2_rn(q1.z, q1.w);
        int packed = tgt | ((src & (NPB - 1)) << 17);
        recbuf[(size_t)pos] = make_int4(u0.i, u1.i, u2.i, packed);
    }
}

// one block (512 thr) per bucket: fused key-stage+count, single-wave shfl scan,
// LDS scatter sort, per-(node,feature) register accumulation, fused epilogue.
__global__ __launch_bounds__(512) void aggregate_kernel(
    const int* __restrict__ gbase, const int4* __restrict__ recbuf,
    const float* __restrict__ x,
    const float* __restrict__ prof, const float* __restrict__ bias,
    float* __restrict__ out) {
    __shared__ float sprof[512];        // 2 KB
    __shared__ int cnt[NPB];
    __shared__ int start[NPB];
    __shared__ int cur[NPB];
    __shared__ int skey[MAX_BE];        // 6 KB
    __shared__ int srec[MAX_BE];        // 6 KB
    __shared__ float acc[NPB * 48];     // 12 KB

    int t = threadIdx.x, b = blockIdx.x;
    sprof[t] = prof[t];
    if (t < NPB) cnt[t] = 0;
    __syncthreads();

    int lo = gbase[b], hi = gbase[b + 1];
    int n = hi - lo; if (n > MAX_BE) n = MAX_BE;
    const int* ri = (const int*)recbuf;

    // fused: stage keys to LDS + count per local node
    for (int k = t; k < n; k += 512) {
        int key = ri[(size_t)(lo + k) * 4 + 3];
        skey[k] = key;
        atomicAdd(&cnt[((unsigned)key) >> 17], 1);
    }
    __syncthreads();

    // single-wave exclusive scan of 64 counters via shfl
    if (t < 64) {
        int v = cnt[t];
        int s = v;
#pragma unroll
        for (int d = 1; d < 64; d <<= 1) {
            int u = __shfl_up(s, d, 64);
            if (t >= d) s += u;
        }
        start[t] = s - v;
        cur[t] = s - v;
    }
    __syncthreads();

    // scatter keys (LDS->LDS) sorted by local node; carries window slot
    for (int k = t; k < n; k += 512) {
        int packed = skey[k];
        int nl = ((unsigned)packed) >> 17;
        int p = atomicAdd(&cur[nl], 1);
        srec[p] = (packed & 0x1FFFF) | (k << 17);   // k < 1536 < 2^11
    }
    __syncthreads();

    // hot loop: thread = (node nl, feature f)
    int nl = t >> 3, f = t & 7;
    float a0r0 = 0.f, a1r0 = 0.f, aIr0 = 0.f, a0r1 = 0.f, a1r1 = 0.f, aIr1 = 0.f;
    int s0 = start[nl], n0 = cnt[nl];
    for (int k = 0; k < n0; ++k) {
        int rec = srec[s0 + k];
        int slot = ((unsigned)rec) >> 17;
        int tgt = rec & 0x1FFFF;
        int4 rv = recbuf[(size_t)(lo + slot)];
        H2I u0, u1, u2; u0.i = rv.x; u1.i = rv.y; u2.i = rv.z;
        float2 f0 = __half22float2(u0.h);   // o0r0.re, o0r1.re
        float2 f1 = __half22float2(u1.h);   // o1r0.re, o1r0.im
        float2 f2 = __half22float2(u2.h);   // o1r1.re, o1r1.im
        float xv = x[tgt * IN_CH + f];
        a0r0 = fmaf(xv, f0.x, a0r0);
        a0r1 = fmaf(xv, f0.y, a0r1);
        a1r0 = fmaf(xv, f1.x, a1r0);
        aIr0 = fmaf(xv, f1.y, aIr0);
        a1r1 = fmaf(xv, f2.x, a1r1);
        aIr1 = fmaf(xv, f2.y, aIr1);
    }
    float* a = acc + nl * 48;
    a[f * 3 + 0] = a0r0;  a[f * 3 + 1] = a1r0;  a[f * 3 + 2] = aIr0;
    a[24 + f * 3 + 0] = a0r1;  a[24 + f * 3 + 1] = a1r1;  a[24 + f * 3 + 2] = aIr1;
    __syncthreads();

    // einsum + magnitude + log-softmax: 64 nodes x 16 classes = 2 passes
#pragma unroll
    for (int pass = 0; pass < 2; ++pass) {
        int nl2 = pass * 32 + (t >> 4);
        int c = t & 15;
        int gnode = b * NPB + nl2;
        if (gnode < N_NODES) {
            float re0 = 0.f, re1 = 0.f, im1 = 0.f;
#pragma unroll
            for (int rr = 0; rr < 2; ++rr) {
#pragma unroll
                for (int ff = 0; ff < 8; ++ff) {
                    int idx = nl2 * 48 + rr * 24 + ff * 3;
                    float w0 = sprof[(0 * 2 + rr) * 128 + c * 8 + ff];
                    float w1 = sprof[(1 * 2 + rr) * 128 + c * 8 + ff];
                    re0 = fmaf(w0, acc[idx + 0], re0);
                    re1 = fmaf(w1, acc[idx + 1], re1);
                    im1 = fmaf(w1, acc[idx + 2], im1);
                }
            }
            float mag = sqrtf(fmaxf(re0 * re0, 1e-12f)) +
                        sqrtf(fmaxf(re1 * re1 + im1 * im1, 1e-12f));
            float logit = mag + bias[c];
            float m = logit;
#pragma unroll
            for (int o = 1; o < 16; o <<= 1) m = fmaxf(m, __shfl_xor(m, o, 16));
            float ex = __expf(logit - m);
            float s = ex;
#pragma unroll
            for (int o = 1; o < 16; o <<= 1) s += __shfl_xor(s, o, 16);
            out[gnode * N_CLASSES + c] = (logit - m) - logf(s);
        }
    }
}

// ======================= fallback (R1 atomic path) =======================

__global__ __launch_bounds__(256) void zero_ws_kernel(float4* __restrict__ ws, int n4) {
    int i = blockIdx.x * blockDim.x + threadIdx.x;
    if (i < n4) ws[i] = make_float4(0.f, 0.f, 0.f, 0.f);
}

__global__ __launch_bounds__(256) void edge_kernel(
    const int* __restrict__ ei, const float* __restrict__ x,
    const float* __restrict__ precomp,
    float* __restrict__ aggrRe, float* __restrict__ aggrIm) {
    int gid = blockIdx.x * blockDim.x + threadIdx.x;
    int e = gid >> 3;
    int f = gid & 7;
    if (e >= N_EDGES) return;
    int src = ei[e];
    int tgt = ei[N_EDGES + e];
    float xv = x[tgt * IN_CH + f];
    const float4* pc = (const float4*)(precomp + (size_t)e * 8);
    float4 p0 = pc[0], p1 = pc[1];
    float* ar = aggrRe + (size_t)src * 32;
    atomicAdd(ar + ((0 * 8 + f) * 2 + 0), xv * p0.x);
    atomicAdd(ar + ((1 * 8 + f) * 2 + 0), xv * p0.z);
    atomicAdd(ar + ((0 * 8 + f) * 2 + 1), xv * p1.x);
    atomicAdd(ar + ((1 * 8 + f) * 2 + 1), xv * p1.z);
    float* ai = aggrIm + (size_t)src * 16;
    atomicAdd(ai + (0 * 8 + f), xv * p1.y);
    atomicAdd(ai + (1 * 8 + f), xv * p1.w);
}

__global__ __launch_bounds__(256) void node_kernel(
    const float* __restrict__ aggrRe, const float* __restrict__ aggrIm,
    const float* __restrict__ prof, const float* __restrict__ bias,
    float* __restrict__ out) {
    __shared__ float sprof[512];
    for (int i = threadIdx.x; i < 512; i += blockDim.x) sprof[i] = prof[i];
    __syncthreads();
    int gid = blockIdx.x * blockDim.x + threadIdx.x;
    int n = gid >> 4;
    int c = gid & 15;
    if (n >= N_NODES) return;
    const float* ar = aggrRe + (size_t)n * 32;
    const float* ai = aggrIm + (size_t)n * 16;
    float re0 = 0.f, re1 = 0.f, im1 = 0.f;
#pragma unroll
    for (int r = 0; r < 2; ++r)
#pragma unroll
        for (int f = 0; f < 8; ++f) {
            float a0 = ar[(r * 8 + f) * 2 + 0];
            float a1 = ar[(r * 8 + f) * 2 + 1];
            float aI = ai[r * 8 + f];
            float w0 = sprof[(0 * 2 + r) * 128 + c * 8 + f];
            float w1 = sprof[(1 * 2 + r) * 128 + c * 8 + f];
            re0 = fmaf(w0, a0, re0);
            re1 = fmaf(w1, a1, re1);
            im1 = fmaf(w1, aI, im1);
        }
    float mag = sqrtf(fmaxf(re0 * re0, 1e-12f)) +
                sqrtf(fmaxf(re1 * re1 + im1 * im1, 1e-12f));
    float logit = mag + bias[c];
    float m = logit;
#pragma unroll
    for (int o = 1; o < 16; o <<= 1) m = fmaxf(m, __shfl_xor(m, o, 16));
    float ex = __expf(logit - m);
    float s = ex;
#pragma unroll
    for (int o = 1; o < 16; o <<= 1) s += __shfl_xor(s, o, 16);
    out[n * N_CLASSES + c] = (logit - m) - logf(s);
}

// ======================= launch =======================

extern "C" void kernel_launch(void* const* d_in, const int* in_sizes, int n_in,
                              void* d_out, int out_size, void* d_ws, size_t ws_size,
                              hipStream_t stream) {
    const float* x       = (const float*)d_in[0];
    const int*   ei      = (const int*)d_in[1];
    const float* precomp = (const float*)d_in[2];
    const float* prof    = (const float*)d_in[4];
    const float* bias    = (const float*)d_in[5];
    float* out = (float*)d_out;

    if (ws_size >= BIN_WS_BYTES) {
        char* ws = (char*)d_ws;
        int4* recbuf = (int4*)(ws + RECBUF_OFF);
        int* bcnt    = (int*)(ws + BCNT_OFF);
        int* colsum  = (int*)(ws + COLSUM_OFF);
        int* gbase   = (int*)(ws + GBASE_OFF);

        hist_kernel<<<NBLK, 1024, 0, stream>>>(ei, bcnt);
        colscan_kernel<<<NB_PAD / 16, 1024, 0, stream>>>(bcnt, colsum);
        base_kernel<<<1, 1024, 0, stream>>>(colsum, gbase);
        bin_kernel<<<NBLK, 1024, 0, stream>>>(ei, precomp, bcnt, gbase, recbuf);
        aggregate_kernel<<<NB, 512, 0, stream>>>(gbase, recbuf, x, prof, bias, out);
    } else {
        float* aggrRe = (float*)d_ws;
        float* aggrIm = aggrRe + AGGR_RE_FLOATS;
        zero_ws_kernel<<<(WS_F4 + 255) / 256, 256, 0, stream>>>((float4*)d_ws, WS_F4);
        int edge_threads = N_EDGES * 8;
        edge_kernel<<<(edge_threads + 255) / 256, 256, 0, stream>>>(ei, x, precomp, aggrRe, aggrIm);
        int node_threads = N_NODES * 16;
        node_kernel<<<(node_threads + 255) / 256, 256, 0, stream>>>(aggrRe, aggrIm, prof, bias, out);
    }
}

// Round 15
// 75.394 us; speedup vs baseline: 1.1877x; 1.1877x over previous
//
#include <hip/hip_runtime.h>
#include <hip/hip_fp16.h>

#define N_NODES 100000
#define N_EDGES 1600000
#define IN_CH 8
#define N_CLASSES 16
// MAX_ORDER+1 = 2, N_RINGS = 2

// bucket = src >> 6  (64 nodes per bucket)
#define NPB 64
#define NPB_SHIFT 6
#define NB ((N_NODES + NPB - 1) / NPB)                // 1563
#define NB_PAD 1568                                   // multiple of 16
#define BIN_T 3125
#define NBLK 512                                      // 512*3125 = 1,600,000 exactly; 2 blocks/CU
#define MAX_BE 1536   // bucket mean 1024, sigma ~32 -> +16 sigma

union H2I { __half2 h; int i; };

// ---------------- binned-path ws layout (bytes) ----------------
// recbuf: int4[N_EDGES] (16B: 3x half2 payload + packed key)
// bcnt: int[NBLK][NB_PAD]; colsum: int[NB_PAD]; gbase: int[NB+1]
#define RECBUF_OFF  0
#define BCNT_OFF    ((size_t)N_EDGES * 16)
#define COLSUM_OFF  (BCNT_OFF + (size_t)NBLK * NB_PAD * 4)
#define GBASE_OFF   (COLSUM_OFF + (size_t)NB_PAD * 4)
#define BIN_WS_BYTES (GBASE_OFF + ((size_t)NB + 4) * 4)

// ---------------- fallback (atomic) ws layout ----------------
#define AGGR_RE_FLOATS (N_NODES * 32)
#define AGGR_IM_FLOATS (N_NODES * 16)
#define WS_FLOATS (AGGR_RE_FLOATS + AGGR_IM_FLOATS)
#define WS_F4 (WS_FLOATS / 4)

// ======================= binned path =======================

// per-block LDS histogram -> coalesced row write (NO global atomics)
__global__ __launch_bounds__(1024) void hist_kernel(const int* __restrict__ ei,
                                                    int* __restrict__ bcnt) {
    __shared__ int h[NB_PAD];
    int t = threadIdx.x;
    for (int i = t; i < NB_PAD; i += 1024) h[i] = 0;
    __syncthreads();
    int base = blockIdx.x * BIN_T;
    int end = base + BIN_T; if (end > N_EDGES) end = N_EDGES;
    for (int e = base + t; e < end; e += 1024)
        atomicAdd(&h[ei[e] >> NPB_SHIFT], 1);
    __syncthreads();
    for (int i = t; i < NB_PAD; i += 1024)
        bcnt[(size_t)blockIdx.x * NB_PAD + i] = h[i];
}

// 98 blocks x 16 buckets: exclusive scan over NBLK rows per bucket, in-place.
// thread (r64 = t>>4, c = t&15); each thread serially handles 8 rows (64*8=512).
__global__ __launch_bounds__(1024) void colscan_kernel(int* __restrict__ bcnt,
                                                       int* __restrict__ colsum) {
    __shared__ int sbuf[16][65];
    int t = threadIdx.x;
    int r64 = t >> 4, c = t & 15;
    int c0 = blockIdx.x * 16;
    int vals[8];
    int partial = 0;
#pragma unroll
    for (int k = 0; k < 8; ++k) {
        int row = r64 * 8 + k;
        int v = bcnt[(size_t)row * NB_PAD + c0 + c];
        vals[k] = v;
        partial += v;
    }
    sbuf[c][r64] = partial;
    __syncthreads();
#pragma unroll
    for (int d = 1; d < 64; d <<= 1) {
        int u = (r64 >= d) ? sbuf[c][r64 - d] : 0;
        __syncthreads();
        sbuf[c][r64] += u;
        __syncthreads();
    }
    int running = sbuf[c][r64] - partial;
#pragma unroll
    for (int k = 0; k < 8; ++k) {
        int row = r64 * 8 + k;
        bcnt[(size_t)row * NB_PAD + c0 + c] = running;
        running += vals[k];
    }
    if (r64 == 63) colsum[c0 + c] = sbuf[c][63];
}

// single block: exclusive scan of colsum (NB entries, 2/thread) -> gbase
__global__ __launch_bounds__(1024) void base_kernel(const int* __restrict__ colsum,
                                                    int* __restrict__ gbase) {
    __shared__ int buf[1024];
    int t = threadIdx.x;
    int i0 = 2 * t, i1 = 2 * t + 1;
    int v0 = (i0 < NB) ? colsum[i0] : 0;
    int v1 = (i1 < NB) ? colsum[i1] : 0;
    buf[t] = v0 + v1;
    __syncthreads();
#pragma unroll
    for (int d = 1; d < 1024; d <<= 1) {
        int u = (t >= d) ? buf[t - d] : 0;
        __syncthreads();
        buf[t] += u;
        __syncthreads();
    }
    int excl = buf[t] - (v0 + v1);
    if (i0 < NB) gbase[i0] = excl;
    if (i1 < NB) gbase[i1] = excl + v0;
    if (t == 1023) gbase[NB] = buf[1023];
}

// bin 16B records into per-bucket runs; bases precomputed -> NO global atomics.
// record: (h2(o0r0.re,o0r1.re), h2(o1r0.re,o1r0.im), h2(o1r1.re,o1r1.im), tgt|nl<<17)
__global__ __launch_bounds__(1024) void bin_kernel(
    const int* __restrict__ ei, const float* __restrict__ precomp,
    const int* __restrict__ bcnt, const int* __restrict__ gbase,
    int4* __restrict__ recbuf) {
    __shared__ int lbase[NB];
    __shared__ int lcnt[NB];
    int t = threadIdx.x;
    for (int i = t; i < NB; i += 1024) {
        lbase[i] = gbase[i] + bcnt[(size_t)blockIdx.x * NB_PAD + i];
        lcnt[i] = 0;
    }
    __syncthreads();
    int base = blockIdx.x * BIN_T;
    int end = base + BIN_T; if (end > N_EDGES) end = N_EDGES;
    for (int e = base + t; e < end; e += 1024) {
        int src = ei[e];
        int tgt = ei[N_EDGES + e];
        int b = src >> NPB_SHIFT;
        int rank = atomicAdd(&lcnt[b], 1);
        size_t pos = (size_t)(lbase[b] + rank);
        const float4* pc = (const float4*)(precomp + (size_t)e * 8);
        float4 q0 = pc[0], q1 = pc[1];
        H2I u0, u1, u2;
        u0.h = __floats2half2_rn(q0.x, q0.z);
        u1.h = __floats2half2_rn(q1.x, q1.y);
        u2.h = __floats2half2_rn(q1.z, q1.w);
        int packed = tgt | ((src & (NPB - 1)) << 17);
        recbuf[pos] = make_int4(u0.i, u1.i, u2.i, packed);
    }
}

// one block (512 thr) per bucket: fused key-stage+count, single-wave shfl scan,
// LDS scatter sort, per-(node,feature) register accumulation, fused epilogue.
__global__ __launch_bounds__(512) void aggregate_kernel(
    const int* __restrict__ gbase, const int4* __restrict__ recbuf,
    const float* __restrict__ x,
    const float* __restrict__ prof, const float* __restrict__ bias,
    float* __restrict__ out) {
    __shared__ float sprof[512];        // 2 KB
    __shared__ int cnt[NPB];
    __shared__ int start[NPB];
    __shared__ int cur[NPB];
    __shared__ int skey[MAX_BE];        // 6 KB
    __shared__ int srec[MAX_BE];        // 6 KB
    __shared__ float acc[NPB * 48];     // 12 KB

    int t = threadIdx.x, b = blockIdx.x;
    sprof[t] = prof[t];
    if (t < NPB) cnt[t] = 0;
    __syncthreads();

    int lo = gbase[b], hi = gbase[b + 1];
    int n = hi - lo; if (n > MAX_BE) n = MAX_BE;
    const int* ri = (const int*)recbuf;

    // fused: stage keys to LDS + count per local node
    for (int k = t; k < n; k += 512) {
        int key = ri[(size_t)(lo + k) * 4 + 3];
        skey[k] = key;
        atomicAdd(&cnt[((unsigned)key) >> 17], 1);
    }
    __syncthreads();

    // single-wave exclusive scan of 64 counters via shfl
    if (t < 64) {
        int v = cnt[t];
        int s = v;
#pragma unroll
        for (int d = 1; d < 64; d <<= 1) {
            int u = __shfl_up(s, d, 64);
            if (t >= d) s += u;
        }
        start[t] = s - v;
        cur[t] = s - v;
    }
    __syncthreads();

    // scatter keys (LDS->LDS) sorted by local node; carries window slot
    for (int k = t; k < n; k += 512) {
        int packed = skey[k];
        int nl = ((unsigned)packed) >> 17;
        int p = atomicAdd(&cur[nl], 1);
        srec[p] = (packed & 0x1FFFF) | (k << 17);   // k < 1536 < 2^11
    }
    __syncthreads();

    // hot loop: thread = (node nl, feature f)
    int nl = t >> 3, f = t & 7;
    float a0r0 = 0.f, a1r0 = 0.f, aIr0 = 0.f, a0r1 = 0.f, a1r1 = 0.f, aIr1 = 0.f;
    int s0 = start[nl], n0 = cnt[nl];
    for (int k = 0; k < n0; ++k) {
        int rec = srec[s0 + k];
        int slot = ((unsigned)rec) >> 17;
        int tgt = rec & 0x1FFFF;
        int4 rv = recbuf[(size_t)(lo + slot)];
        H2I u0, u1, u2; u0.i = rv.x; u1.i = rv.y; u2.i = rv.z;
        float2 f0 = __half22float2(u0.h);   // o0r0.re, o0r1.re
        float2 f1 = __half22float2(u1.h);   // o1r0.re, o1r0.im
        float2 f2 = __half22float2(u2.h);   // o1r1.re, o1r1.im
        float xv = x[tgt * IN_CH + f];
        a0r0 = fmaf(xv, f0.x, a0r0);
        a0r1 = fmaf(xv, f0.y, a0r1);
        a1r0 = fmaf(xv, f1.x, a1r0);
        aIr0 = fmaf(xv, f1.y, aIr0);
        a1r1 = fmaf(xv, f2.x, a1r1);
        aIr1 = fmaf(xv, f2.y, aIr1);
    }
    float* a = acc + nl * 48;
    a[f * 3 + 0] = a0r0;  a[f * 3 + 1] = a1r0;  a[f * 3 + 2] = aIr0;
    a[24 + f * 3 + 0] = a0r1;  a[24 + f * 3 + 1] = a1r1;  a[24 + f * 3 + 2] = aIr1;
    __syncthreads();

    // einsum + magnitude + log-softmax: 64 nodes x 16 classes = 2 passes
#pragma unroll
    for (int pass = 0; pass < 2; ++pass) {
        int nl2 = pass * 32 + (t >> 4);
        int c = t & 15;
        int gnode = b * NPB + nl2;
        if (gnode < N_NODES) {
            float re0 = 0.f, re1 = 0.f, im1 = 0.f;
#pragma unroll
            for (int rr = 0; rr < 2; ++rr) {
#pragma unroll
                for (int ff = 0; ff < 8; ++ff) {
                    int idx = nl2 * 48 + rr * 24 + ff * 3;
                    float w0 = sprof[(0 * 2 + rr) * 128 + c * 8 + ff];
                    float w1 = sprof[(1 * 2 + rr) * 128 + c * 8 + ff];
                    re0 = fmaf(w0, acc[idx + 0], re0);
                    re1 = fmaf(w1, acc[idx + 1], re1);
                    im1 = fmaf(w1, acc[idx + 2], im1);
                }
            }
            float mag = sqrtf(fmaxf(re0 * re0, 1e-12f)) +
                        sqrtf(fmaxf(re1 * re1 + im1 * im1, 1e-12f));
            float logit = mag + bias[c];
            float m = logit;
#pragma unroll
            for (int o = 1; o < 16; o <<= 1) m = fmaxf(m, __shfl_xor(m, o, 16));
            float ex = __expf(logit - m);
            float s = ex;
#pragma unroll
            for (int o = 1; o < 16; o <<= 1) s += __shfl_xor(s, o, 16);
            out[gnode * N_CLASSES + c] = (logit - m) - logf(s);
        }
    }
}

// ======================= fallback (R1 atomic path) =======================

__global__ __launch_bounds__(256) void zero_ws_kernel(float4* __restrict__ ws, int n4) {
    int i = blockIdx.x * blockDim.x + threadIdx.x;
    if (i < n4) ws[i] = make_float4(0.f, 0.f, 0.f, 0.f);
}

__global__ __launch_bounds__(256) void edge_kernel(
    const int* __restrict__ ei, const float* __restrict__ x,
    const float* __restrict__ precomp,
    float* __restrict__ aggrRe, float* __restrict__ aggrIm) {
    int gid = blockIdx.x * blockDim.x + threadIdx.x;
    int e = gid >> 3;
    int f = gid & 7;
    if (e >= N_EDGES) return;
    int src = ei[e];
    int tgt = ei[N_EDGES + e];
    float xv = x[tgt * IN_CH + f];
    const float4* pc = (const float4*)(precomp + (size_t)e * 8);
    float4 p0 = pc[0], p1 = pc[1];
    float* ar = aggrRe + (size_t)src * 32;
    atomicAdd(ar + ((0 * 8 + f) * 2 + 0), xv * p0.x);
    atomicAdd(ar + ((1 * 8 + f) * 2 + 0), xv * p0.z);
    atomicAdd(ar + ((0 * 8 + f) * 2 + 1), xv * p1.x);
    atomicAdd(ar + ((1 * 8 + f) * 2 + 1), xv * p1.z);
    float* ai = aggrIm + (size_t)src * 16;
    atomicAdd(ai + (0 * 8 + f), xv * p1.y);
    atomicAdd(ai + (1 * 8 + f), xv * p1.w);
}

__global__ __launch_bounds__(256) void node_kernel(
    const float* __restrict__ aggrRe, const float* __restrict__ aggrIm,
    const float* __restrict__ prof, const float* __restrict__ bias,
    float* __restrict__ out) {
    __shared__ float sprof[512];
    for (int i = threadIdx.x; i < 512; i += blockDim.x) sprof[i] = prof[i];
    __syncthreads();
    int gid = blockIdx.x * blockDim.x + threadIdx.x;
    int n = gid >> 4;
    int c = gid & 15;
    if (n >= N_NODES) return;
    const float* ar = aggrRe + (size_t)n * 32;
    const float* ai = aggrIm + (size_t)n * 16;
    float re0 = 0.f, re1 = 0.f, im1 = 0.f;
#pragma unroll
    for (int r = 0; r < 2; ++r)
#pragma unroll
        for (int f = 0; f < 8; ++f) {
            float a0 = ar[(r * 8 + f) * 2 + 0];
            float a1 = ar[(r * 8 + f) * 2 + 1];
            float aI = ai[r * 8 + f];
            float w0 = sprof[(0 * 2 + r) * 128 + c * 8 + f];
            float w1 = sprof[(1 * 2 + r) * 128 + c * 8 + f];
            re0 = fmaf(w0, a0, re0);
            re1 = fmaf(w1, a1, re1);
            im1 = fmaf(w1, aI, im1);
        }
    float mag = sqrtf(fmaxf(re0 * re0, 1e-12f)) +
                sqrtf(fmaxf(re1 * re1 + im1 * im1, 1e-12f));
    float logit = mag + bias[c];
    float m = logit;
#pragma unroll
    for (int o = 1; o < 16; o <<= 1) m = fmaxf(m, __shfl_xor(m, o, 16));
    float ex = __expf(logit - m);
    float s = ex;
#pragma unroll
    for (int o = 1; o < 16; o <<= 1) s += __shfl_xor(s, o, 16);
    out[n * N_CLASSES + c] = (logit - m) - logf(s);
}

// ======================= launch =======================

extern "C" void kernel_launch(void* const* d_in, const int* in_sizes, int n_in,
                              void* d_out, int out_size, void* d_ws, size_t ws_size,
                              hipStream_t stream) {
    const float* x       = (const float*)d_in[0];
    const int*   ei      = (const int*)d_in[1];
    const float* precomp = (const float*)d_in[2];
    const float* prof    = (const float*)d_in[4];
    const float* bias    = (const float*)d_in[5];
    float* out = (float*)d_out;

    if (ws_size >= BIN_WS_BYTES) {
        char* ws = (char*)d_ws;
        int4* recbuf = (int4*)(ws + RECBUF_OFF);
        int* bcnt    = (int*)(ws + BCNT_OFF);
        int* colsum  = (int*)(ws + COLSUM_OFF);
        int* gbase   = (int*)(ws + GBASE_OFF);

        hist_kernel<<<NBLK, 1024, 0, stream>>>(ei, bcnt);
        colscan_kernel<<<NB_PAD / 16, 1024, 0, stream>>>(bcnt, colsum);
        base_kernel<<<1, 1024, 0, stream>>>(colsum, gbase);
        bin_kernel<<<NBLK, 1024, 0, stream>>>(ei, precomp, bcnt, gbase, recbuf);
        aggregate_kernel<<<NB, 512, 0, stream>>>(gbase, recbuf, x, prof, bias, out);
    } else {
        float* aggrRe = (float*)d_ws;
        float* aggrIm = aggrRe + AGGR_RE_FLOATS;
        zero_ws_kernel<<<(WS_F4 + 255) / 256, 256, 0, stream>>>((float4*)d_ws, WS_F4);
        int edge_threads = N_EDGES * 8;
        edge_kernel<<<(edge_threads + 255) / 256, 256, 0, stream>>>(ei, x, precomp, aggrRe, aggrIm);
        int node_threads = N_NODES * 16;
        node_kernel<<<(node_threads + 255) / 256, 256, 0, stream>>>(aggrRe, aggrIm, prof, bias, out);
    }
}

// Round 16
// 71.986 us; speedup vs baseline: 1.2439x; 1.0473x over previous
//
#include <hip/hip_runtime.h>
#include <hip/hip_fp16.h>

#define N_NODES 100000
#define N_EDGES 1600000
#define IN_CH 8
#define N_CLASSES 16
// MAX_ORDER+1 = 2, N_RINGS = 2

// bucket = src >> 6  (64 nodes per bucket)
#define NPB 64
#define NPB_SHIFT 6
#define NB ((N_NODES + NPB - 1) / NPB)                // 1563
#define NB_PAD 1568                                   // multiple of 16
#define BIN_T 3125
#define NBLK 512                                      // 512*3125 = 1,600,000 exactly
#define MAX_BE 1536   // bucket mean 1024, sigma ~32 -> +16 sigma

// XCD-grouped row permutation: tiles on the same XCD (b%8 equal) get adjacent
// position chunks within each bucket -> same-line appends stay in one L2.
__device__ __forceinline__ int tile_row(int b) { return ((b & 7) << 6) | (b >> 3); }

union H2I { __half2 h; int i; };

// ---------------- binned-path ws layout (bytes) ----------------
// recbuf: int4[N_EDGES] (16B: 3x half2 payload + packed key)
// bcnt: int[NBLK][NB_PAD]; colsum: int[NB_PAD]; gbase: int[NB+1]
#define RECBUF_OFF  0
#define BCNT_OFF    ((size_t)N_EDGES * 16)
#define COLSUM_OFF  (BCNT_OFF + (size_t)NBLK * NB_PAD * 4)
#define GBASE_OFF   (COLSUM_OFF + (size_t)NB_PAD * 4)
#define BIN_WS_BYTES (GBASE_OFF + ((size_t)NB + 4) * 4)

// ---------------- fallback (atomic) ws layout ----------------
#define AGGR_RE_FLOATS (N_NODES * 32)
#define AGGR_IM_FLOATS (N_NODES * 16)
#define WS_FLOATS (AGGR_RE_FLOATS + AGGR_IM_FLOATS)
#define WS_F4 (WS_FLOATS / 4)

// ======================= binned path =======================

// per-block LDS histogram -> coalesced row write (NO global atomics)
__global__ __launch_bounds__(1024) void hist_kernel(const int* __restrict__ ei,
                                                    int* __restrict__ bcnt) {
    __shared__ int h[NB_PAD];
    int t = threadIdx.x;
    for (int i = t; i < NB_PAD; i += 1024) h[i] = 0;
    __syncthreads();
    int base = blockIdx.x * BIN_T;
    int end = base + BIN_T; if (end > N_EDGES) end = N_EDGES;
    for (int e = base + t; e < end; e += 1024)
        atomicAdd(&h[ei[e] >> NPB_SHIFT], 1);
    __syncthreads();
    size_t row = (size_t)tile_row(blockIdx.x);
    for (int i = t; i < NB_PAD; i += 1024)
        bcnt[row * NB_PAD + i] = h[i];
}

// 98 blocks x 16 buckets: exclusive scan over NBLK rows per bucket, in-place.
// thread (r64 = t>>4, c = t&15); each thread serially handles 8 rows (64*8=512).
__global__ __launch_bounds__(1024) void colscan_kernel(int* __restrict__ bcnt,
                                                       int* __restrict__ colsum) {
    __shared__ int sbuf[16][65];
    int t = threadIdx.x;
    int r64 = t >> 4, c = t & 15;
    int c0 = blockIdx.x * 16;
    int vals[8];
    int partial = 0;
#pragma unroll
    for (int k = 0; k < 8; ++k) {
        int row = r64 * 8 + k;
        int v = bcnt[(size_t)row * NB_PAD + c0 + c];
        vals[k] = v;
        partial += v;
    }
    sbuf[c][r64] = partial;
    __syncthreads();
#pragma unroll
    for (int d = 1; d < 64; d <<= 1) {
        int u = (r64 >= d) ? sbuf[c][r64 - d] : 0;
        __syncthreads();
        sbuf[c][r64] += u;
        __syncthreads();
    }
    int running = sbuf[c][r64] - partial;
#pragma unroll
    for (int k = 0; k < 8; ++k) {
        int row = r64 * 8 + k;
        bcnt[(size_t)row * NB_PAD + c0 + c] = running;
        running += vals[k];
    }
    if (r64 == 63) colsum[c0 + c] = sbuf[c][63];
}

// single block: exclusive scan of colsum (NB entries, 2/thread) -> gbase
__global__ __launch_bounds__(1024) void base_kernel(const int* __restrict__ colsum,
                                                    int* __restrict__ gbase) {
    __shared__ int buf[1024];
    int t = threadIdx.x;
    int i0 = 2 * t, i1 = 2 * t + 1;
    int v0 = (i0 < NB) ? colsum[i0] : 0;
    int v1 = (i1 < NB) ? colsum[i1] : 0;
    buf[t] = v0 + v1;
    __syncthreads();
#pragma unroll
    for (int d = 1; d < 1024; d <<= 1) {
        int u = (t >= d) ? buf[t - d] : 0;
        __syncthreads();
        buf[t] += u;
        __syncthreads();
    }
    int excl = buf[t] - (v0 + v1);
    if (i0 < NB) gbase[i0] = excl;
    if (i1 < NB) gbase[i1] = excl + v0;
    if (t == 1023) gbase[NB] = buf[1023];
}

// bin 16B records into per-bucket runs; bases precomputed -> NO global atomics.
// record: (h2(o0r0.re,o0r1.re), h2(o1r0.re,o1r0.im), h2(o1r1.re,o1r1.im), tgt|nl<<17)
__global__ __launch_bounds__(1024) void bin_kernel(
    const int* __restrict__ ei, const float* __restrict__ precomp,
    const int* __restrict__ bcnt, const int* __restrict__ gbase,
    int4* __restrict__ recbuf) {
    __shared__ int lbase[NB];
    __shared__ int lcnt[NB];
    int t = threadIdx.x;
    size_t row = (size_t)tile_row(blockIdx.x);
    for (int i = t; i < NB; i += 1024) {
        lbase[i] = gbase[i] + bcnt[row * NB_PAD + i];
        lcnt[i] = 0;
    }
    __syncthreads();
    int base = blockIdx.x * BIN_T;
    int end = base + BIN_T; if (end > N_EDGES) end = N_EDGES;
    for (int e = base + t; e < end; e += 1024) {
        int src = ei[e];
        int tgt = ei[N_EDGES + e];
        int b = src >> NPB_SHIFT;
        int rank = atomicAdd(&lcnt[b], 1);
        size_t pos = (size_t)(lbase[b] + rank);
        const float4* pc = (const float4*)(precomp + (size_t)e * 8);
        float4 q0 = pc[0], q1 = pc[1];
        H2I u0, u1, u2;
        u0.h = __floats2half2_rn(q0.x, q0.z);
        u1.h = __floats2half2_rn(q1.x, q1.y);
        u2.h = __floats2half2_rn(q1.z, q1.w);
        int packed = tgt | ((src & (NPB - 1)) << 17);
        recbuf[pos] = make_int4(u0.i, u1.i, u2.i, packed);
    }
}

// one block (512 thr) per bucket: fused key-stage+count, single-wave shfl scan,
// LDS scatter sort, per-(node,feature) register accumulation, fused epilogue.
__global__ __launch_bounds__(512) void aggregate_kernel(
    const int* __restrict__ gbase, const int4* __restrict__ recbuf,
    const float* __restrict__ x,
    const float* __restrict__ prof, const float* __restrict__ bias,
    float* __restrict__ out) {
    __shared__ float sprof[512];        // 2 KB
    __shared__ int cnt[NPB];
    __shared__ int start[NPB];
    __shared__ int cur[NPB];
    __shared__ int skey[MAX_BE];        // 6 KB
    __shared__ int srec[MAX_BE];        // 6 KB
    __shared__ float acc[NPB * 48];     // 12 KB

    int t = threadIdx.x, b = blockIdx.x;
    sprof[t] = prof[t];
    if (t < NPB) cnt[t] = 0;
    __syncthreads();

    int lo = gbase[b], hi = gbase[b + 1];
    int n = hi - lo; if (n > MAX_BE) n = MAX_BE;
    const int* ri = (const int*)recbuf;

    // fused: stage keys to LDS + count per local node
    for (int k = t; k < n; k += 512) {
        int key = ri[(size_t)(lo + k) * 4 + 3];
        skey[k] = key;
        atomicAdd(&cnt[((unsigned)key) >> 17], 1);
    }
    __syncthreads();

    // single-wave exclusive scan of 64 counters via shfl
    if (t < 64) {
        int v = cnt[t];
        int s = v;
#pragma unroll
        for (int d = 1; d < 64; d <<= 1) {
            int u = __shfl_up(s, d, 64);
            if (t >= d) s += u;
        }
        start[t] = s - v;
        cur[t] = s - v;
    }
    __syncthreads();

    // scatter keys (LDS->LDS) sorted by local node; carries window slot
    for (int k = t; k < n; k += 512) {
        int packed = skey[k];
        int nl = ((unsigned)packed) >> 17;
        int p = atomicAdd(&cur[nl], 1);
        srec[p] = (packed & 0x1FFFF) | (k << 17);   // k < 1536 < 2^11
    }
    __syncthreads();

    // hot loop: thread = (node nl, feature f)
    int nl = t >> 3, f = t & 7;
    float a0r0 = 0.f, a1r0 = 0.f, aIr0 = 0.f, a0r1 = 0.f, a1r1 = 0.f, aIr1 = 0.f;
    int s0 = start[nl], n0 = cnt[nl];
    for (int k = 0; k < n0; ++k) {
        int rec = srec[s0 + k];
        int slot = ((unsigned)rec) >> 17;
        int tgt = rec & 0x1FFFF;
        int4 rv = recbuf[(size_t)(lo + slot)];
        H2I u0, u1, u2; u0.i = rv.x; u1.i = rv.y; u2.i = rv.z;
        float2 f0 = __half22float2(u0.h);   // o0r0.re, o0r1.re
        float2 f1 = __half22float2(u1.h);   // o1r0.re, o1r0.im
        float2 f2 = __half22float2(u2.h);   // o1r1.re, o1r1.im
        float xv = x[tgt * IN_CH + f];
        a0r0 = fmaf(xv, f0.x, a0r0);
        a0r1 = fmaf(xv, f0.y, a0r1);
        a1r0 = fmaf(xv, f1.x, a1r0);
        aIr0 = fmaf(xv, f1.y, aIr0);
        a1r1 = fmaf(xv, f2.x, a1r1);
        aIr1 = fmaf(xv, f2.y, aIr1);
    }
    float* a = acc + nl * 48;
    a[f * 3 + 0] = a0r0;  a[f * 3 + 1] = a1r0;  a[f * 3 + 2] = aIr0;
    a[24 + f * 3 + 0] = a0r1;  a[24 + f * 3 + 1] = a1r1;  a[24 + f * 3 + 2] = aIr1;
    __syncthreads();

    // einsum + magnitude + log-softmax: 64 nodes x 16 classes = 2 passes
#pragma unroll
    for (int pass = 0; pass < 2; ++pass) {
        int nl2 = pass * 32 + (t >> 4);
        int c = t & 15;
        int gnode = b * NPB + nl2;
        if (gnode < N_NODES) {
            float re0 = 0.f, re1 = 0.f, im1 = 0.f;
#pragma unroll
            for (int rr = 0; rr < 2; ++rr) {
#pragma unroll
                for (int ff = 0; ff < 8; ++ff) {
                    int idx = nl2 * 48 + rr * 24 + ff * 3;
                    float w0 = sprof[(0 * 2 + rr) * 128 + c * 8 + ff];
                    float w1 = sprof[(1 * 2 + rr) * 128 + c * 8 + ff];
                    re0 = fmaf(w0, acc[idx + 0], re0);
                    re1 = fmaf(w1, acc[idx + 1], re1);
                    im1 = fmaf(w1, acc[idx + 2], im1);
                }
            }
            float mag = sqrtf(fmaxf(re0 * re0, 1e-12f)) +
                        sqrtf(fmaxf(re1 * re1 + im1 * im1, 1e-12f));
            float logit = mag + bias[c];
            float m = logit;
#pragma unroll
            for (int o = 1; o < 16; o <<= 1) m = fmaxf(m, __shfl_xor(m, o, 16));
            float ex = __expf(logit - m);
            float s = ex;
#pragma unroll
            for (int o = 1; o < 16; o <<= 1) s += __shfl_xor(s, o, 16);
            out[gnode * N_CLASSES + c] = (logit - m) - logf(s);
        }
    }
}

// ======================= fallback (R1 atomic path) =======================

__global__ __launch_bounds__(256) void zero_ws_kernel(float4* __restrict__ ws, int n4) {
    int i = blockIdx.x * blockDim.x + threadIdx.x;
    if (i < n4) ws[i] = make_float4(0.f, 0.f, 0.f, 0.f);
}

__global__ __launch_bounds__(256) void edge_kernel(
    const int* __restrict__ ei, const float* __restrict__ x,
    const float* __restrict__ precomp,
    float* __restrict__ aggrRe, float* __restrict__ aggrIm) {
    int gid = blockIdx.x * blockDim.x + threadIdx.x;
    int e = gid >> 3;
    int f = gid & 7;
    if (e >= N_EDGES) return;
    int src = ei[e];
    int tgt = ei[N_EDGES + e];
    float xv = x[tgt * IN_CH + f];
    const float4* pc = (const float4*)(precomp + (size_t)e * 8);
    float4 p0 = pc[0], p1 = pc[1];
    float* ar = aggrRe + (size_t)src * 32;
    atomicAdd(ar + ((0 * 8 + f) * 2 + 0), xv * p0.x);
    atomicAdd(ar + ((1 * 8 + f) * 2 + 0), xv * p0.z);
    atomicAdd(ar + ((0 * 8 + f) * 2 + 1), xv * p1.x);
    atomicAdd(ar + ((1 * 8 + f) * 2 + 1), xv * p1.z);
    float* ai = aggrIm + (size_t)src * 16;
    atomicAdd(ai + (0 * 8 + f), xv * p1.y);
    atomicAdd(ai + (1 * 8 + f), xv * p1.w);
}

__global__ __launch_bounds__(256) void node_kernel(
    const float* __restrict__ aggrRe, const float* __restrict__ aggrIm,
    const float* __restrict__ prof, const float* __restrict__ bias,
    float* __restrict__ out) {
    __shared__ float sprof[512];
    for (int i = threadIdx.x; i < 512; i += blockDim.x) sprof[i] = prof[i];
    __syncthreads();
    int gid = blockIdx.x * blockDim.x + threadIdx.x;
    int n = gid >> 4;
    int c = gid & 15;
    if (n >= N_NODES) return;
    const float* ar = aggrRe + (size_t)n * 32;
    const float* ai = aggrIm + (size_t)n * 16;
    float re0 = 0.f, re1 = 0.f, im1 = 0.f;
#pragma unroll
    for (int r = 0; r < 2; ++r)
#pragma unroll
        for (int f = 0; f < 8; ++f) {
            float a0 = ar[(r * 8 + f) * 2 + 0];
            float a1 = ar[(r * 8 + f) * 2 + 1];
            float aI = ai[r * 8 + f];
            float w0 = sprof[(0 * 2 + r) * 128 + c * 8 + f];
            float w1 = sprof[(1 * 2 + r) * 128 + c * 8 + f];
            re0 = fmaf(w0, a0, re0);
            re1 = fmaf(w1, a1, re1);
            im1 = fmaf(w1, aI, im1);
        }
    float mag = sqrtf(fmaxf(re0 * re0, 1e-12f)) +
                sqrtf(fmaxf(re1 * re1 + im1 * im1, 1e-12f));
    float logit = mag + bias[c];
    float m = logit;
#pragma unroll
    for (int o = 1; o < 16; o <<= 1) m = fmaxf(m, __shfl_xor(m, o, 16));
    float ex = __expf(logit - m);
    float s = ex;
#pragma unroll
    for (int o = 1; o < 16; o <<= 1) s += __shfl_xor(s, o, 16);
    out[n * N_CLASSES + c] = (logit - m) - logf(s);
}

// ======================= launch =======================

extern "C" void kernel_launch(void* const* d_in, const int* in_sizes, int n_in,
                              void* d_out, int out_size, void* d_ws, size_t ws_size,
                              hipStream_t stream) {
    const float* x       = (const float*)d_in[0];
    const int*   ei      = (const int*)d_in[1];
    const float* precomp = (const float*)d_in[2];
    const float* prof    = (const float*)d_in[4];
    const float* bias    = (const float*)d_in[5];
    float* out = (float*)d_out;

    if (ws_size >= BIN_WS_BYTES) {
        char* ws = (char*)d_ws;
        int4* recbuf = (int4*)(ws + RECBUF_OFF);
        int* bcnt    = (int*)(ws + BCNT_OFF);
        int* colsum  = (int*)(ws + COLSUM_OFF);
        int* gbase   = (int*)(ws + GBASE_OFF);

        hist_kernel<<<NBLK, 1024, 0, stream>>>(ei, bcnt);
        colscan_kernel<<<NB_PAD / 16, 1024, 0, stream>>>(bcnt, colsum);
        base_kernel<<<1, 1024, 0, stream>>>(colsum, gbase);
        bin_kernel<<<NBLK, 1024, 0, stream>>>(ei, precomp, bcnt, gbase, recbuf);
        aggregate_kernel<<<NB, 512, 0, stream>>>(gbase, recbuf, x, prof, bias, out);
    } else {
        float* aggrRe = (float*)d_ws;
        float* aggrIm = aggrRe + AGGR_RE_FLOATS;
        zero_ws_kernel<<<(WS_F4 + 255) / 256, 256, 0, stream>>>((float4*)d_ws, WS_F4);
        int edge_threads = N_EDGES * 8;
        edge_kernel<<<(edge_threads + 255) / 256, 256, 0, stream>>>(ei, x, precomp, aggrRe, aggrIm);
        int node_threads = N_NODES * 16;
        node_kernel<<<(node_threads + 255) / 256, 256, 0, stream>>>(aggrRe, aggrIm, prof, bias, out);
    }
}